// Round 7
// baseline (130.463 us; speedup 1.0000x reference)
//
#include <hip/hip_runtime.h>
#include <stdint.h>

typedef uint16_t u16;
typedef unsigned long long u64;
typedef __attribute__((ext_vector_type(8))) short    bf16x8;  // 8 bf16 (4 VGPRs)
typedef __attribute__((ext_vector_type(8))) uint16_t u16x8;
typedef __attribute__((ext_vector_type(4))) float    f32x4;

#define B_    2
#define N_    100000
#define K_    26
#define CIN_  32
#define COUT_ 32

#define XT_ROWS  (N_ + 1)
// xt2: [2][B][XT_ROWS][16] bf16 rows of 32B; per (h,b) table = 3.2MB (fits 4MB XCD L2)
#define XT2_BYTES ((size_t)2 * B_ * XT_ROWS * 16 * 2)   // 12,800,128 bytes

// ---- prep kernel geometry ----
#define TCHUNK      64
#define TBLK_PER_B  ((N_ + TCHUNK - 1) / TCHUNK)     // 1563
#define TBLKS       (B_ * TBLK_PER_B)                // 3126
#define WBLKS       13                               // 13 * 256 chunks = 3328 = 26624/8
#define PREP_GRID   (TBLKS + 1 + WBLKS)

// ---- conv kernel geometry ----
// Resident grid: 1568 blocks (196 slots x 8 XCDs), 4 waves/block.
// Per batch: 784 blocks = 3136 waves; 6250 16-node tiles -> 2 tiles/wave
// (waves 3114..3135 have 1). All blocks co-resident => phases stay aligned
// across the grid, so per XCD-half only ONE 3.2MB table is hot at a time.
#define CSLOTS      196
#define CONV_GRID   (CSLOTS * 8)                     // 1568
#define WAVES_PB    (CSLOTS * 4 * 4)                 // 3136 waves per batch
#define TILES_PB    (N_ / 16)                        // 6250 (exact, no tail)
#define WOFF        (16 * 26 * 16)                   // o+16 offset in Wb2 elems

__device__ __forceinline__ u16 f2bf(float f) {
    union { float f; uint32_t u; } v; v.f = f;
    return (u16)((v.u + 0x7FFFu + ((v.u >> 16) & 1u)) >> 16);  // RNE
}

// Transpose inp [B][CIN][N] f32 -> xt2 [2][B][N+1][16] bf16 (32B rows),
// fill row at n==N, W -> Wb2 [2][32][26][16] bf16.
__global__ __launch_bounds__(256) void prep_kernel(
    const float* __restrict__ inp, const float* __restrict__ W,
    const float* __restrict__ fill, u16* __restrict__ xt2, u16* __restrict__ Wb2)
{
    int tid = threadIdx.x;
    int blk = blockIdx.x;
    if (blk >= TBLKS) {
        int job = blk - TBLKS;
        if (job == 0) {
            if (tid < 64) {
                int h = tid >> 5, b = (tid >> 4) & 1, c = tid & 15;
                xt2[((size_t)(h * B_ + b) * XT_ROWS + N_) * 16 + c] = f2bf(fill[h * 16 + c]);
            }
        } else {
            int i = (job - 1) * 256 + tid;            // chunk of 8 bf16; 3328 total
            int c8 = i & 1;
            int t  = i >> 1;
            int k  = t % 26;
            int t2 = t / 26;
            int o  = t2 & 31;
            int h  = t2 >> 5;
            const float* src = W + o * 832 + k * 32 + h * 16 + c8 * 8;  // 32B aligned
            float4 x = ((const float4*)src)[0], y = ((const float4*)src)[1];
            u16x8 v;
            v[0] = f2bf(x.x); v[1] = f2bf(x.y); v[2] = f2bf(x.z); v[3] = f2bf(x.w);
            v[4] = f2bf(y.x); v[5] = f2bf(y.y); v[6] = f2bf(y.z); v[7] = f2bf(y.w);
            *(u16x8*)(Wb2 + (size_t)i * 8) = v;
        }
        return;
    }
    __shared__ u16 tile[64][40];                      // pad: rows 80B
    int b  = blk / TBLK_PER_B;
    int n0 = (blk % TBLK_PER_B) * TCHUNK;
    const float* inb = inp + (size_t)b * CIN_ * N_;
    #pragma unroll
    for (int it = 0; it < 8; ++it) {
        int idx = it * 256 + tid;
        int c = idx >> 6, n = idx & 63;
        if (n0 + n < N_) tile[n][c] = f2bf(inb[(size_t)c * N_ + n0 + n]);
    }
    __syncthreads();
    int n = tid >> 2, seg = tid & 3;                  // seg: (h = seg>>1, c8 = seg&1)
    if (n0 + n < N_) {
        u16x8 v = *(const u16x8*)&tile[n][seg * 8];
        int h = seg >> 1, c8 = seg & 1;
        *(u16x8*)(xt2 + ((size_t)(h * B_ + b) * XT_ROWS + n0 + n) * 16 + c8 * 8) = v;
    }
}

#define MFMA16(a, b, c) __builtin_amdgcn_mfma_f32_16x16x32_bf16((a), (b), (c), 0, 0, 0)

// Gather + MFMA GEMM, channel-split two-phase, resident grid.
// Indices staged to LDS ONCE before phase 0 (coalesced NT reads) -> phases
// touch L2 only with gathers (3.2MB table) + W (26KB, L1). NT out stores.
// K=32 MFMA step = 2 neighbours x 16 ch; lane g = (nbr parity gsel, ch chunk c8).
// Batch 0 -> XCDs 0-3, batch 1 -> XCDs 4-7 (bid&7 -> XCD heuristic).
__global__ __launch_bounds__(256, 6) void conv_kernel(
    const u16* __restrict__ xt2, const u16* __restrict__ Wb2,
    const int* __restrict__ nbr, const float* __restrict__ bias,
    float* __restrict__ out)
{
    __shared__ u64 idxl[4][2][16 * 13];               // 13,312 B
    int tid  = threadIdx.x;
    int bid  = blockIdx.x;
    int xcd  = bid & 7, slot = bid >> 3;
    int b    = xcd >> 2;
    int wv   = tid >> 6;
    int lane = tid & 63;
    int l15  = lane & 15, g = lane >> 4;
    int gsel = g >> 1, c8 = g & 1;
    int w    = (slot * 4 + (xcd & 3)) * 4 + wv;       // wave id within batch [0,3136)

    const int* nbb  = nbr + (size_t)b * N_ * K_;
    float*     outb = out + (size_t)b * COUT_ * N_;

    int t0 = w;                                       // always < 6250
    int t1 = w + WAVES_PB;
    bool v1 = (t1 < TILES_PB);

    // ---- stage neighbour indices to LDS (coalesced: 64 lanes x 8B chunks) ----
    {
        const u64* src0 = (const u64*)(nbb) + (size_t)t0 * 208;   // 16*26 ints = 208 u64
        u64* dst0 = &idxl[wv][0][0];
        #pragma unroll
        for (int r = 0; r < 3; ++r)
            dst0[lane + r * 64] = __builtin_nontemporal_load(src0 + lane + r * 64);
        if (lane < 16) dst0[lane + 192] = __builtin_nontemporal_load(src0 + lane + 192);
        if (v1) {
            const u64* src1 = (const u64*)(nbb) + (size_t)t1 * 208;
            u64* dst1 = &idxl[wv][1][0];
            #pragma unroll
            for (int r = 0; r < 3; ++r)
                dst1[lane + r * 64] = __builtin_nontemporal_load(src1 + lane + r * 64);
            if (lane < 16) dst1[lane + 192] = __builtin_nontemporal_load(src1 + lane + 192);
        }
    }
    __syncthreads();

    f32x4 acc[2][2];
    acc[0][0] = 0.0f; acc[0][1] = 0.0f; acc[1][0] = 0.0f; acc[1][1] = 0.0f;

    #pragma unroll 1
    for (int h = 0; h < 2; ++h) {                     // temporal phase per channel-half
        const u16* xg = xt2 + (size_t)(h * B_ + b) * XT_ROWS * 16 + c8 * 8;
        const u16* wg = Wb2 + ((size_t)(h * 32 + l15) * 26 + gsel) * 16 + c8 * 8;

        #pragma unroll                                 // static i (rule #20)
        for (int i = 0; i < 2; ++i) {
            if (i == 1 && !v1) continue;               // wave-uniform skip
            const u64* qp = &idxl[wv][i][l15 * 13];    // node-major [16][13]
            bf16x8 f[2], wa0[2], wa1[2];
            u64 qc = qp[0];
            wa0[0] = *(const bf16x8*)(wg);
            wa1[0] = *(const bf16x8*)(wg + WOFF);
            {
                uint32_t i0 = (uint32_t)(gsel ? (qc >> 32) : qc);
                f[0] = *(const bf16x8*)(xg + ((size_t)i0 << 4));
            }
            u64 qn = qp[1];
            #pragma unroll
            for (int kp = 0; kp < 13; ++kp) {
                const int cur = kp & 1, nxt = cur ^ 1;
                if (kp < 12) {
                    wa0[nxt] = *(const bf16x8*)(wg + (kp + 1) * 32);
                    wa1[nxt] = *(const bf16x8*)(wg + WOFF + (kp + 1) * 32);
                    uint32_t ix = (uint32_t)(gsel ? (qn >> 32) : qn);
                    f[nxt] = *(const bf16x8*)(xg + ((size_t)ix << 4));
                    if (kp < 11) qn = qp[kp + 2];
                }
                __builtin_amdgcn_sched_barrier(0);     // pin prefetch above MFMAs
                acc[i][0] = MFMA16(wa0[cur], f[cur], acc[i][0]);
                acc[i][1] = MFMA16(wa1[cur], f[cur], acc[i][1]);
            }
        }
        __syncthreads();                               // keep block phase-aligned
    }

    // ---- epilogue: D col = lane&15 -> node, D row = g*4+r -> o ----
    #pragma unroll
    for (int i = 0; i < 2; ++i) {
        if (i == 1 && !v1) continue;
        int node = (i ? t1 : t0) * 16 + l15;           // exact tiling, no clamp
        #pragma unroll
        for (int r = 0; r < 4; ++r) {
            float b0 = bias[g * 4 + r];
            float b1 = bias[g * 4 + r + 16];
            __builtin_nontemporal_store(acc[i][0][r] + b0, &outb[(size_t)(g * 4 + r) * N_ + node]);
            __builtin_nontemporal_store(acc[i][1][r] + b1, &outb[(size_t)(g * 4 + r + 16) * N_ + node]);
        }
    }
}

extern "C" void kernel_launch(void* const* d_in, const int* in_sizes, int n_in,
                              void* d_out, int out_size, void* d_ws, size_t ws_size,
                              hipStream_t stream) {
    (void)in_sizes; (void)n_in; (void)out_size; (void)ws_size;
    const float* inp  = (const float*)d_in[0];
    const int*   nbr  = (const int*)d_in[1];
    const float* W    = (const float*)d_in[2];
    const float* bias = (const float*)d_in[3];
    const float* fill = (const float*)d_in[4];
    float* out = (float*)d_out;

    u16* xt2 = (u16*)d_ws;                             // [2][B][N+1][16] bf16
    u16* Wb2 = (u16*)((char*)d_ws + XT2_BYTES);        // [2][32][26][16] bf16

    prep_kernel<<<PREP_GRID, 256, 0, stream>>>(inp, W, fill, xt2, Wb2);
    conv_kernel<<<CONV_GRID, 256, 0, stream>>>(xt2, Wb2, nbr, bias, out);
}